// Round 3
// baseline (163.764 us; speedup 1.0000x reference)
//
#include <hip/hip_runtime.h>

// Div (quantized qint16), evaluated to match a float64 numpy reference.
//
// out = clip(round(q1*s1 * (recip_q(q2*s2)*TS) / os)), recip_q = piecewise
// {const, line, dense LUT(256), sparse LUT(256), line, const} of 1/|x|, signed.
//
// r1/r2 post-mortem: absmax bit-identical (1152.0) across f32-div and
// f64-emulated-f32-div kernels => hipcc f32 '/' is already IEEE-correct
// (v_div_scale/fmas/fixup), and the f32-faithful index path does NOT match
// the harness 'np' reference. => reference is evaluated in float64.
// This kernel does all discontinuity-amplified math in f64:
//  * ax = |q2|*s2 exact in f64 (41-bit product)
//  * idx = rint((ax-xmin)*inv_step) in f64 (~1e-14 err vs ~1e-9 decision gap)
//  * LUT values: np.linspace f64 semantics (product rounded before adding
//    start -- asm barrier stops fma contraction; endpoint forced) +
//    correctly-rounded f64 divides (device f64 '/' is IEEE).
//  * final: prod/os = q1*rq*200/65535 exactly (s1==os); parity => distance
//    from half-integers >= 1/131070 >> association error => bit-exact rint.
// Memory-bound: 512 MiB read + 256 MiB write -> ~122 us @ 6.3 TB/s.

#define TS64     (2.0 / 0.01 / 65535.0)     // f64, same two roundings as Python
#define STEPD    (0.99 / 255.0)
#define STEPS    (6.0 / 255.0)
#define INVSTEPD (1.0 / (0.99 / 255.0))
#define INVSTEPS (1.0 / (6.0 / 255.0))

__device__ __forceinline__ void build_tables(double* tbl) {
    const int t = threadIdx.x;
    if (t < 256) {
        double pd = (double)t * STEPD;     // np.linspace: y = arange*step ...
        double ps = (double)t * STEPS;
        asm volatile("" : "+v"(pd));       // keep the product rounding (no fma)
        asm volatile("" : "+v"(ps));
        double xd = 0.01 + pd;             // ... then y += start
        double xs = 1.0 + ps;
        if (t == 255) { xd = 1.0; xs = 7.0; }  // linspace endpoint overwrite
        // quant(1/xs): both divides correctly rounded f64 (device IEEE '/')
        double qd = rint((1.0 / xd) / TS64);
        double qs = rint((1.0 / xs) / TS64);
        tbl[t]       = fmin(fmax(qd, -32768.0), 32767.0);
        tbl[t + 256] = fmin(fmax(qs, -32768.0), 32767.0);
    }
    __syncthreads();
}

__device__ __forceinline__ float div_elem(int q1i, int q2i, double s2d, double Kd,
                                          const double* tbl) {
    const double ax = fabs((double)q2i * s2d);   // EXACT in f64
    const bool dense = ax < 1.0;
    const double xmin = dense ? 0.01 : 1.0;
    const double inv  = dense ? INVSTEPD : INVSTEPS;
    // ~2ulp-accurate f64 quotient; realizable ax sit >=~1e-9 from half-ints
    double idxd = rint((ax - xmin) * inv);
    idxd = fmin(fmax(idxd, 0.0), 255.0);
    double rq = tbl[(int)idxd + (dense ? 0 : 256)];

    if (__builtin_expect(!(ax >= 0.01 && ax < 7.0), 0)) {   // never taken here
        if (ax < 0.01) {
            // left const & left line both saturate quant -> 32767 for all
            // realizable ax (granularity 2e-4: y >= ~2100 >> 100.0008)
            rq = 32767.0;
        } else if (ax < 20.0) {
            const double y0 = 1.0 / 7.0;
            const double dy = 0.05 - 1.0 / 7.0;
            double y = y0 + (ax - 7.0) * dy / 13.0;
            rq = fmin(fmax(rint(y / TS64), -32768.0), 32767.0);
        } else {
            rq = 16.0;                      // quant(1/20)
        }
    }
    rq = (q2i < 0) ? -rq : rq;
    double o = rint((double)q1i * Kd * rq); // Kd = s1*TS/os (f64)
    o = fmin(fmax(o, -32768.0), 32767.0);
    return (float)o;
}

__global__ void __launch_bounds__(256)
div_q16_vec4(const int4* __restrict__ q1, const int4* __restrict__ q2,
             const float* __restrict__ s1p, const float* __restrict__ s2p,
             const float* __restrict__ osp, float4* __restrict__ out, int nvec) {
    __shared__ double tbl[512];
    build_tables(tbl);
    const double s2d = (double)s2p[0];
    const double Kd  = (double)s1p[0] * TS64 / (double)osp[0];
    const int stride = gridDim.x * blockDim.x;
    for (int i = blockIdx.x * blockDim.x + threadIdx.x; i < nvec; i += stride) {
        const int4 a = q1[i];
        const int4 b = q2[i];
        float4 o;
        o.x = div_elem(a.x, b.x, s2d, Kd, tbl);
        o.y = div_elem(a.y, b.y, s2d, Kd, tbl);
        o.z = div_elem(a.z, b.z, s2d, Kd, tbl);
        o.w = div_elem(a.w, b.w, s2d, Kd, tbl);
        out[i] = o;
    }
}

__global__ void __launch_bounds__(256)
div_q16_tail(const int* __restrict__ q1, const int* __restrict__ q2,
             const float* __restrict__ s1p, const float* __restrict__ s2p,
             const float* __restrict__ osp, float* __restrict__ out,
             int base, int n) {
    __shared__ double tbl[512];
    build_tables(tbl);
    const double s2d = (double)s2p[0];
    const double Kd  = (double)s1p[0] * TS64 / (double)osp[0];
    const int i = base + blockIdx.x * (int)blockDim.x + threadIdx.x;
    if (i < n) out[i] = div_elem(q1[i], q2[i], s2d, Kd, tbl);
}

extern "C" void kernel_launch(void* const* d_in, const int* in_sizes, int n_in,
                              void* d_out, int out_size, void* d_ws, size_t ws_size,
                              hipStream_t stream) {
    const int n = in_sizes[0];
    const int* q1 = (const int*)d_in[0];
    const int* q2 = (const int*)d_in[1];
    const float* s1 = (const float*)d_in[2];
    const float* s2 = (const float*)d_in[3];
    const float* os = (const float*)d_in[4];
    float* out = (float*)d_out;

    const int nvec = n >> 2;
    const int block = 256;
    if (nvec > 0) {
        int grid = (nvec + block - 1) / block;
        if (grid > 2048) grid = 2048;   // ~8 blocks/CU, grid-stride the rest
        div_q16_vec4<<<grid, block, 0, stream>>>(
            (const int4*)q1, (const int4*)q2, s1, s2, os, (float4*)out, nvec);
    }
    const int tail = n & 3;
    if (tail) {
        div_q16_tail<<<1, block, 0, stream>>>(q1, q2, s1, s2, os, out,
                                              n - tail, n);
    }
}